// Round 12
// baseline (124.414 us; speedup 1.0000x reference)
//
#include <hip/hip_runtime.h>
#include <stdint.h>

typedef unsigned short u16;
typedef __bf16 bf16x8 __attribute__((ext_vector_type(8)));
typedef float f32x4 __attribute__((ext_vector_type(4)));
typedef float f32x16 __attribute__((ext_vector_type(16)));

__device__ __forceinline__ u16 f2bf(float f) {
  uint32_t u = __builtin_bit_cast(uint32_t, f);
  u += 0x7FFFu + ((u >> 16) & 1u);
  return (u16)(u >> 16);
}
__device__ __forceinline__ float bf2f(u16 v) {
  return __builtin_bit_cast(float, ((uint32_t)v) << 16);
}

#if __has_builtin(__builtin_amdgcn_exp2f)
__device__ __forceinline__ float exp2_fast(float x) { return __builtin_amdgcn_exp2f(x); }
#else
__device__ __forceinline__ float exp2_fast(float x) { return exp2f(x); }
#endif

__device__ __forceinline__ void gload_lds16(const u16* g, u16* l) {
  __builtin_amdgcn_global_load_lds(
      (const __attribute__((address_space(1))) uint32_t*)g,
      (__attribute__((address_space(3))) uint32_t*)l, 16, 0, 0);
}

__device__ __forceinline__ uint32_t cvtpk(float lo, float hi) {
  uint32_t r;
  asm("v_cvt_pk_bf16_f32 %0, %1, %2" : "=v"(r) : "v"(lo), "v"(hi));
  return r;
}
// v_permlane32_swap_b32: a.row1 <-> b.row0  (rows = 32-lane halves)
__device__ __forceinline__ void plswap(uint32_t& a, uint32_t& b) {
  asm volatile("v_permlane32_swap_b32 %0, %1" : "+v"(a), "+v"(b));
}

// ---------------- fused prep ----------------
// [0,4096): x->bf16 ; [4096,7168): WqkvT ; [7168,8192): WoutT ; [8192,8448): cond proj
__global__ __launch_bounds__(256) void prep_kernel(
    const float* __restrict__ x, const float* __restrict__ Wqkv,
    const float* __restrict__ Wout, const float* __restrict__ label,
    const float* __restrict__ Wk, const float* __restrict__ Wv,
    u16* __restrict__ xb, u16* __restrict__ WqkvT, u16* __restrict__ WoutT,
    u16* __restrict__ ek, u16* __restrict__ ev, float qscale) {
  const int b = blockIdx.x;
  if (b < 4096) {
    int i = (b * 256 + threadIdx.x) * 8;
    float4 a = *(const float4*)(x + i);
    float4 c = *(const float4*)(x + i + 4);
    union { u16 u[8]; uint4 v; } r;
    r.u[0] = f2bf(a.x); r.u[1] = f2bf(a.y); r.u[2] = f2bf(a.z); r.u[3] = f2bf(a.w);
    r.u[4] = f2bf(c.x); r.u[5] = f2bf(c.y); r.u[6] = f2bf(c.z); r.u[7] = f2bf(c.w);
    *(uint4*)(xb + i) = r.v;
  } else if (b < 7168) {
    int id = (b - 4096) * 256 + threadIdx.x;
    int k = id & 511, nn = id >> 9;
    float v = Wqkv[(size_t)k * 1536 + nn];
    if (nn < 512) v *= qscale;
    WqkvT[id] = f2bf(v);
  } else if (b < 8192) {
    int id = (b - 7168) * 256 + threadIdx.x;
    int k = id & 511, nn = id >> 9;
    WoutT[id] = f2bf(Wout[(size_t)k * 512 + nn]);
  } else {
    // cond proj: 256 blocks = 2 (k/v) x 16 rows x 8 col-chunks; 4-way K-split + LDS reduce
    __shared__ float sdata[256];
    const int bb = b - 8192;
    const int chunk = bb & 7, row = (bb >> 3) & 15;
    const float* W = (bb & 128) ? Wv : Wk;
    u16* o = (bb & 128) ? ev : ek;
    const int tid = threadIdx.x;
    const int col = chunk * 64 + (tid & 63);
    const int ks = tid >> 6;  // 0..3, 128 k each
    const float* lr = label + row * 512 + ks * 128;
    const float* wp = W + (size_t)(ks * 128) * 512 + col;
    float acc = 0.f;
#pragma unroll 8
    for (int i = 0; i < 128; ++i)
      acc = fmaf(lr[i], wp[(size_t)i * 512], acc);
    sdata[tid] = acc;
    __syncthreads();
    if (tid < 64) {
      float t = sdata[tid] + sdata[tid + 64] + sdata[tid + 128] + sdata[tid + 192];
      o[row * 512 + chunk * 64 + tid] = f2bf(t);
    }
  }
}

// ---------------- GEMM v4: BM=256 x BN(192|128), BK=64, 8 waves (2Mx4N) ----------------
// per-wave 128x(48|32); 2-buffer LDS, counted vmcnt, hoisted swizzle offsets.
template <int MODE>
__global__ __launch_bounds__(512, 2) void gemm_bt_kernel(
    const u16* __restrict__ A, const u16* __restrict__ B,
    u16* __restrict__ OQ, u16* __restrict__ OKb, u16* __restrict__ OVT,
    float* __restrict__ OF, int K, int N) {
  constexpr int BN = (MODE == 0) ? 192 : 128;
  constexpr int NI = BN / 64;
  constexpr int NRB = BN / 64;
  constexpr int NBY = (MODE == 0) ? 8 : 4;
  constexpr int VM = 4 + NRB;

  __shared__ __align__(16) u16 As[2][256 * 64];
  __shared__ __align__(16) u16 Bs[2][BN * 64];

  const int tid = threadIdx.x;
  const int w = tid >> 6, lane = tid & 63;
  const int l15 = lane & 15, lg = lane >> 4;
  const int wr = w >> 2, wc = w & 3;

  const int q8 = gridDim.x >> 3;
  const int wg = (blockIdx.x & 7) * q8 + (blockIdx.x >> 3);
  const int bx = wg / NBY, by = wg % NBY;

  const int srow = tid >> 3, schunk = tid & 7;
  const u16* Ag = A + (size_t)(bx * 256 + srow) * K + ((schunk ^ (srow & 7)) * 8);
  const u16* Bg = B + (size_t)(by * BN + srow) * K + ((schunk ^ (srow & 7)) * 8);

  int aoff[8][2], boff[NI][2];
#pragma unroll
  for (int mi = 0; mi < 8; ++mi)
#pragma unroll
    for (int ks = 0; ks < 2; ++ks) {
      const int row = wr * 128 + mi * 16 + l15;
      aoff[mi][ks] = row * 64 + (((ks * 4 + lg) ^ (row & 7)) * 8);
    }
#pragma unroll
  for (int ni = 0; ni < NI; ++ni)
#pragma unroll
    for (int ks = 0; ks < 2; ++ks) {
      const int row = wc * (BN / 4) + ni * 16 + l15;
      boff[ni][ks] = row * 64 + (((ks * 4 + lg) ^ (row & 7)) * 8);
    }

  f32x4 acc[8][NI] = {};

  const int nt = K >> 6;
#define STAGE(buf, k0)                                                       \
  {                                                                          \
    _Pragma("unroll") for (int ra = 0; ra < 4; ++ra)                         \
        gload_lds16(Ag + (k0) + (size_t)(ra * 64) * K,                       \
                    &As[buf][(ra * 64 + w * 8) * 64]);                       \
    _Pragma("unroll") for (int rb = 0; rb < NRB; ++rb)                       \
        gload_lds16(Bg + (k0) + (size_t)(rb * 64) * K,                       \
                    &Bs[buf][(rb * 64 + w * 8) * 64]);                       \
  }
#define COMPUTE(cb)                                                          \
  {                                                                          \
    const u16* Ab = &As[cb][0];                                              \
    const u16* Bb = &Bs[cb][0];                                              \
    _Pragma("unroll") for (int ks = 0; ks < 2; ++ks) {                       \
      bf16x8 a[8], b[NI];                                                    \
      _Pragma("unroll") for (int mi = 0; mi < 8; ++mi)                       \
          a[mi] = *(const bf16x8*)&Ab[aoff[mi][ks]];                         \
      _Pragma("unroll") for (int ni = 0; ni < NI; ++ni)                      \
          b[ni] = *(const bf16x8*)&Bb[boff[ni][ks]];                         \
      __builtin_amdgcn_s_setprio(1);                                         \
      _Pragma("unroll") for (int mi = 0; mi < 8; ++mi)                       \
          _Pragma("unroll") for (int ni = 0; ni < NI; ++ni)                  \
              acc[mi][ni] = __builtin_amdgcn_mfma_f32_16x16x32_bf16(          \
                  a[mi], b[ni], acc[mi][ni], 0, 0, 0);                       \
      __builtin_amdgcn_s_setprio(0);                                         \
    }                                                                        \
  }

  STAGE(0, 0);
  STAGE(1, 64);

  for (int t = 0; t < nt - 1; ++t) {
    if constexpr (VM == 7)
      asm volatile("s_waitcnt vmcnt(7)" ::: "memory");
    else
      asm volatile("s_waitcnt vmcnt(6)" ::: "memory");
    __builtin_amdgcn_s_barrier();
    __builtin_amdgcn_sched_barrier(0);
    COMPUTE(t & 1);
    if (t + 2 < nt) {
      __builtin_amdgcn_s_barrier();
      __builtin_amdgcn_sched_barrier(0);
      STAGE(t & 1, (t + 2) * 64);
    }
  }
  asm volatile("s_waitcnt vmcnt(0)" ::: "memory");
  __builtin_amdgcn_s_barrier();
  __builtin_amdgcn_sched_barrier(0);
  COMPUTE((nt - 1) & 1);
#undef STAGE
#undef COMPUTE

  const int row0 = bx * 256 + wr * 128 + lg * 4;
  if constexpr (MODE == 1) {
#pragma unroll
    for (int mi = 0; mi < 8; ++mi)
#pragma unroll
      for (int ni = 0; ni < NI; ++ni) {
        int col = by * BN + wc * (BN / 4) + ni * 16 + l15;
#pragma unroll
        for (int r = 0; r < 4; ++r)
          OF[(size_t)(row0 + mi * 16 + r) * N + col] = acc[mi][ni][r];
      }
  } else {
#pragma unroll
    for (int mi = 0; mi < 8; ++mi)
#pragma unroll
      for (int ni = 0; ni < NI; ++ni) {
        const int gcol = by * BN + wc * (BN / 4) + ni * 16 + l15;
        const int sect = gcol >> 9;
        const int colL = gcol & 511;
        if (sect < 2) {
          u16* O = sect ? OKb : OQ;
#pragma unroll
          for (int r = 0; r < 4; ++r)
            O[(size_t)(row0 + mi * 16 + r) * 512 + colL] = f2bf(acc[mi][ni][r]);
        } else {
          int h = colL >> 6, dh = colL & 63;
          int rr = row0 + mi * 16;
          int bn = rr >> 10, t0 = rr & 1023;
          ushort4 pk;
          pk.x = f2bf(acc[mi][ni][0]);
          pk.y = f2bf(acc[mi][ni][1]);
          pk.z = f2bf(acc[mi][ni][2]);
          pk.w = f2bf(acc[mi][ni][3]);
          *(ushort4*)&OVT[(size_t)((bn * 8 + h) * 64 + dh) * 1024 + t0] = pk;
        }
      }
  }
}

// ---------------- fused flash attention v7: 64q/wave, 2-wave blocks, dbuf via syncthreads ----------------
// grid: 1024 = 128 heads x 8 q-tiles of 128. block: 128 (2 waves x 64 q). 4 blocks/CU.
// psum rowsum in VALU (no rowsum MFMA); one __syncthreads per tile (drain = dbuf handoff).
__global__ __launch_bounds__(128, 2) void attn_kernel(
    const u16* __restrict__ Qb, const u16* __restrict__ Kb, const u16* __restrict__ VTb,
    const u16* __restrict__ ekb, const u16* __restrict__ evb, u16* __restrict__ Ob) {
  __shared__ __align__(16) u16 Kl[2][64 * 64];
  __shared__ __align__(16) u16 Vl[2][64 * 64];

  const int tid = threadIdx.x;  // 0..127
  const int w = tid >> 6, lane = tid & 63;
  const int l31 = lane & 31, hi = lane >> 5;
  // XCD swizzle (1024 % 8 == 0, bijective)
  const int lb = (blockIdx.x & 7) * 128 + (blockIdx.x >> 3);
  const int head = lb >> 3, qt = lb & 7;
  const int bn = head >> 3, h = head & 7;
  const int q0 = qt * 128 + w * 64;

  // ---- gload_lds staging: wave w covers rows [w*32, w*32+32) in 4 issues of 8 rows ----
  const int srow = lane >> 3;                 // 0..7 within an 8-row issue
  const int schunk = lane & 7;
  const u16* Kg0 = Kb + (size_t)(bn * 1024 + w * 32 + srow) * 512 + h * 64;
  const u16* Vg0 = VTb + (size_t)(head * 64 + w * 32 + srow) * 1024;
  // pre-swizzled source column for each of 4 row-groups (row = w*32 + i*8 + srow)
  int scol[4];
#pragma unroll
  for (int i = 0; i < 4; ++i)
    scol[i] = ((schunk ^ ((w * 32 + i * 8 + srow) & 7)) * 8);

#define STAGE(buf, j0)                                                        \
  {                                                                           \
    _Pragma("unroll") for (int i = 0; i < 4; ++i)                             \
        gload_lds16(Kg0 + (size_t)((j0) + i * 8) * 512 + scol[i],             \
                    &Kl[buf][(w * 32 + i * 8) * 64]);                         \
    _Pragma("unroll") for (int i = 0; i < 4; ++i)                             \
        gload_lds16(Vg0 + (j0) + (size_t)(i * 8) * 1024 + scol[i],            \
                    &Vl[buf][(w * 32 + i * 8) * 64]);                         \
  }

  STAGE(0, 0);

  // ---- Q fragments (B-operand): qs-set q = q0 + qs*32 + l31, k(d) = c*16 + hi*8 + j ----
  bf16x8 qf[2][4];
#pragma unroll
  for (int qs = 0; qs < 2; ++qs)
#pragma unroll
    for (int c = 0; c < 4; ++c)
      qf[qs][c] = *(const bf16x8*)(Qb + (size_t)(bn * 1024 + q0 + qs * 32 + l31) * 512 +
                                   h * 64 + c * 16 + hi * 8);

  // ---- conditioning token prologue (v4/v6 math) + psum init ----
  f32x16 acc[2][2];
  float psum[2];
  {
#pragma unroll
    for (int qs = 0; qs < 2; ++qs) {
      float dot = 0.f;
#pragma unroll
      for (int c = 0; c < 4; ++c) {
        bf16x8 ekf = *(const bf16x8*)(ekb + bn * 512 + h * 64 + c * 16 + hi * 8);
#pragma unroll
        for (int j = 0; j < 8; ++j)
          dot += (float)qf[qs][c][j] * (float)ekf[j];
      }
      uint32_t a = __builtin_bit_cast(uint32_t, dot), b = a;
      plswap(a, b);
      float part = (lane < 32) ? __builtin_bit_cast(float, b) : __builtin_bit_cast(float, a);
      float pe = exp2_fast(dot + part);
      psum[qs] = (hi == 0) ? pe : 0.f;

      union { u16 u[8]; bf16x8 v; } pef, evf[2];
#pragma unroll
      for (int j = 0; j < 8; ++j) pef.u[j] = 0;
      if (hi == 0) pef.u[0] = f2bf(pe);
#pragma unroll
      for (int dt = 0; dt < 2; ++dt) {
#pragma unroll
        for (int j = 0; j < 8; ++j) evf[dt].u[j] = 0;
        if (hi == 0) evf[dt].u[0] = evb[bn * 512 + h * 64 + dt * 32 + l31];
      }
      f32x16 z = {};
#pragma unroll
      for (int dt = 0; dt < 2; ++dt)
        acc[qs][dt] = __builtin_amdgcn_mfma_f32_32x32x16_bf16(pef.v, evf[dt].v, z, 0, 0, 0);
    }
  }

  __syncthreads();  // tile 0 staged & visible

  // ---- main loop: 16 K/V tiles of 64; dbuf, ONE barrier per tile ----
  for (int jt = 0; jt < 16; ++jt) {
    const int buf = jt & 1;
    if (jt < 15) STAGE(buf ^ 1, (jt + 1) * 64);  // DMA overlaps compute below

#pragma unroll
    for (int sub = 0; sub < 2; ++sub) {
      // K A-frags: lane row kv = sub*32 + l31
      const int rk = sub * 32 + l31;
      bf16x8 kb[4];
#pragma unroll
      for (int c = 0; c < 4; ++c)
        kb[c] = *(const bf16x8*)&Kl[buf][rk * 64 + (((c * 2 + hi) ^ (rk & 7)) * 8)];

      // S^T = K @ Q^T per qs-set (kb shared across both)
      f32x16 s[2] = {};
      __builtin_amdgcn_s_setprio(1);
#pragma unroll
      for (int c = 0; c < 4; ++c) {
        s[0] = __builtin_amdgcn_mfma_f32_32x32x16_bf16(kb[c], qf[0][c], s[0], 0, 0, 0);
        s[1] = __builtin_amdgcn_mfma_f32_32x32x16_bf16(kb[c], qf[1][c], s[1], 0, 0, 0);
      }
      __builtin_amdgcn_s_setprio(0);

      // exp2 -> psum -> pack -> permlane -> PV A-frags, per qs
      bf16x8 pa[2][2];
#pragma unroll
      for (int qs = 0; qs < 2; ++qs) {
        uint32_t wd[8];
        float ps0 = 0.f, ps1 = 0.f;
#pragma unroll
        for (int i = 0; i < 8; ++i) {
          float e0 = exp2_fast(s[qs][2 * i]);
          float e1 = exp2_fast(s[qs][2 * i + 1]);
          ps0 += e0;
          ps1 += e1;
          wd[i] = cvtpk(e0, e1);
        }
        psum[qs] += ps0 + ps1;
        plswap(wd[0], wd[2]);
        plswap(wd[1], wd[3]);
        plswap(wd[4], wd[6]);
        plswap(wd[5], wd[7]);
        union { uint32_t w[4]; bf16x8 v; } f0, f1;
        f0.w[0] = wd[0]; f0.w[1] = wd[1]; f0.w[2] = wd[2]; f0.w[3] = wd[3];
        f1.w[0] = wd[4]; f1.w[1] = wd[5]; f1.w[2] = wd[6]; f1.w[3] = wd[7];
        pa[qs][0] = f0.v;
        pa[qs][1] = f1.v;
      }

      // PV: acc[qs][dt] += P @ V  (vb shared across qs)
#pragma unroll
      for (int dt = 0; dt < 2; ++dt) {
        const int rv = dt * 32 + l31;
        bf16x8 vb0 = *(const bf16x8*)&Vl[buf][rv * 64 + (((sub * 4 + hi) ^ (rv & 7)) * 8)];
        bf16x8 vb1 = *(const bf16x8*)&Vl[buf][rv * 64 + (((sub * 4 + 2 + hi) ^ (rv & 7)) * 8)];
        __builtin_amdgcn_s_setprio(1);
#pragma unroll
        for (int qs = 0; qs < 2; ++qs) {
          acc[qs][dt] = __builtin_amdgcn_mfma_f32_32x32x16_bf16(pa[qs][0], vb0, acc[qs][dt], 0, 0, 0);
          acc[qs][dt] = __builtin_amdgcn_mfma_f32_32x32x16_bf16(pa[qs][1], vb1, acc[qs][dt], 0, 0, 0);
        }
        __builtin_amdgcn_s_setprio(0);
      }
    }

    __syncthreads();  // reads of buf done + stage(jt+1) drained (vmcnt 0)
  }
#undef STAGE

  // ---- rowsum combine + normalize + store ----
#pragma unroll
  for (int qs = 0; qs < 2; ++qs) {
    uint32_t a = __builtin_bit_cast(uint32_t, psum[qs]), b = a;
    plswap(a, b);
    float other = (lane < 32) ? __builtin_bit_cast(float, b) : __builtin_bit_cast(float, a);
    float lsum = psum[qs] + other;  // full rowsum for q = qs-set col l31
#pragma unroll
    for (int r = 0; r < 16; ++r) {
      const int qloc = (r & 3) + 8 * (r >> 2) + 4 * hi;
      const float ls = __shfl(lsum, qloc);  // lane qloc (<32) holds q=qloc's sum
      const float inv = 1.0f / ls;
      const int q = q0 + qs * 32 + qloc;
      u16* op = Ob + (size_t)(bn * 1024 + q) * 512 + h * 64 + l31;
      op[0] = f2bf(acc[qs][0][r] * inv);
      op[32] = f2bf(acc[qs][1][r] * inv);
    }
  }
}

// ---------------- launcher ----------------
extern "C" void kernel_launch(void* const* d_in, const int* in_sizes, int n_in,
                              void* d_out, int out_size, void* d_ws, size_t ws_size,
                              hipStream_t stream) {
  (void)in_sizes; (void)n_in; (void)out_size; (void)ws_size;
  const float* x     = (const float*)d_in[0];
  const float* label = (const float*)d_in[1];
  const float* Wqkv  = (const float*)d_in[2];
  const float* Wk    = (const float*)d_in[3];
  const float* Wv    = (const float*)d_in[4];
  const float* Wout  = (const float*)d_in[5];
  float* out = (float*)d_out;

  char* ws = (char*)d_ws;
  u16* xb    = (u16*)(ws);                 // 16 MB, reused as attention-out after GEMM1
  u16* WqkvT = (u16*)(ws + 16777216);      // 1.5 MB
  u16* WoutT = (u16*)(ws + 18350080);      // 0.5 MB
  u16* ekb   = (u16*)(ws + 18874368);      // 16 KB
  u16* evb   = (u16*)(ws + 18890752);      // 16 KB
  u16* Qbuf  = (u16*)(ws + 18907136);      // 16 MB
  u16* Kbuf  = (u16*)(ws + 35684352);      // 16 MB
  u16* VTbuf = (u16*)(ws + 52461568);      // 16 MB

  const float qscale = 0.125f * 1.4426950408889634f;

  prep_kernel<<<8448, 256, 0, stream>>>(x, Wqkv, Wout, label, Wk, Wv,
                                        xb, WqkvT, WoutT, ekb, evb, qscale);

  gemm_bt_kernel<0><<<512, 512, 0, stream>>>(xb, WqkvT, Qbuf, Kbuf, VTbuf, nullptr, 512, 1536);

  attn_kernel<<<1024, 128, 0, stream>>>(Qbuf, Kbuf, VTbuf, ekb, evb, xb);

  gemm_bt_kernel<1><<<256, 512, 0, stream>>>(xb, WoutT, nullptr, nullptr, nullptr, out, 512, 512);
}

// Round 13
// 117.205 us; speedup vs baseline: 1.0615x; 1.0615x over previous
//
#include <hip/hip_runtime.h>
#include <stdint.h>

typedef unsigned short u16;
typedef __bf16 bf16x8 __attribute__((ext_vector_type(8)));
typedef float f32x4 __attribute__((ext_vector_type(4)));
typedef float f32x16 __attribute__((ext_vector_type(16)));

__device__ __forceinline__ u16 f2bf(float f) {
  uint32_t u = __builtin_bit_cast(uint32_t, f);
  u += 0x7FFFu + ((u >> 16) & 1u);
  return (u16)(u >> 16);
}
__device__ __forceinline__ float bf2f(u16 v) {
  return __builtin_bit_cast(float, ((uint32_t)v) << 16);
}

#if __has_builtin(__builtin_amdgcn_exp2f)
__device__ __forceinline__ float exp2_fast(float x) { return __builtin_amdgcn_exp2f(x); }
#else
__device__ __forceinline__ float exp2_fast(float x) { return exp2f(x); }
#endif

__device__ __forceinline__ void gload_lds16(const u16* g, u16* l) {
  __builtin_amdgcn_global_load_lds(
      (const __attribute__((address_space(1))) uint32_t*)g,
      (__attribute__((address_space(3))) uint32_t*)l, 16, 0, 0);
}

__device__ __forceinline__ uint32_t cvtpk(float lo, float hi) {
  uint32_t r;
  asm("v_cvt_pk_bf16_f32 %0, %1, %2" : "=v"(r) : "v"(lo), "v"(hi));
  return r;
}
// v_permlane32_swap_b32: a.row1 <-> b.row0  (rows = 32-lane halves)
__device__ __forceinline__ void plswap(uint32_t& a, uint32_t& b) {
  asm volatile("v_permlane32_swap_b32 %0, %1" : "+v"(a), "+v"(b));
}

// ---------------- fused prep ----------------
// [0,4096): x->bf16 ; [4096,7168): WqkvT ; [7168,8192): WoutT ; [8192,8448): cond proj
__global__ __launch_bounds__(256) void prep_kernel(
    const float* __restrict__ x, const float* __restrict__ Wqkv,
    const float* __restrict__ Wout, const float* __restrict__ label,
    const float* __restrict__ Wk, const float* __restrict__ Wv,
    u16* __restrict__ xb, u16* __restrict__ WqkvT, u16* __restrict__ WoutT,
    u16* __restrict__ ek, u16* __restrict__ ev, float qscale) {
  const int b = blockIdx.x;
  if (b < 4096) {
    int i = (b * 256 + threadIdx.x) * 8;
    float4 a = *(const float4*)(x + i);
    float4 c = *(const float4*)(x + i + 4);
    union { u16 u[8]; uint4 v; } r;
    r.u[0] = f2bf(a.x); r.u[1] = f2bf(a.y); r.u[2] = f2bf(a.z); r.u[3] = f2bf(a.w);
    r.u[4] = f2bf(c.x); r.u[5] = f2bf(c.y); r.u[6] = f2bf(c.z); r.u[7] = f2bf(c.w);
    *(uint4*)(xb + i) = r.v;
  } else if (b < 7168) {
    int id = (b - 4096) * 256 + threadIdx.x;
    int k = id & 511, nn = id >> 9;
    float v = Wqkv[(size_t)k * 1536 + nn];
    if (nn < 512) v *= qscale;
    WqkvT[id] = f2bf(v);
  } else if (b < 8192) {
    int id = (b - 7168) * 256 + threadIdx.x;
    int k = id & 511, nn = id >> 9;
    WoutT[id] = f2bf(Wout[(size_t)k * 512 + nn]);
  } else {
    // cond proj: 256 blocks = 2 (k/v) x 16 rows x 8 col-chunks; 4-way K-split + LDS reduce
    __shared__ float sdata[256];
    const int bb = b - 8192;
    const int chunk = bb & 7, row = (bb >> 3) & 15;
    const float* W = (bb & 128) ? Wv : Wk;
    u16* o = (bb & 128) ? ev : ek;
    const int tid = threadIdx.x;
    const int col = chunk * 64 + (tid & 63);
    const int ks = tid >> 6;  // 0..3, 128 k each
    const float* lr = label + row * 512 + ks * 128;
    const float* wp = W + (size_t)(ks * 128) * 512 + col;
    float acc = 0.f;
#pragma unroll 8
    for (int i = 0; i < 128; ++i)
      acc = fmaf(lr[i], wp[(size_t)i * 512], acc);
    sdata[tid] = acc;
    __syncthreads();
    if (tid < 64) {
      float t = sdata[tid] + sdata[tid + 64] + sdata[tid + 128] + sdata[tid + 192];
      o[row * 512 + chunk * 64 + tid] = f2bf(t);
    }
  }
}

// ---------------- GEMM v5: BM=128 x BN(192|128), BK=64, 4 waves, 2 blocks/CU ----------------
// Same verified sync skeleton as v4 (counted vmcnt + dual barrier); LDS <= 80KB so TWO
// independent blocks share each CU and fill each other's barrier bubbles.
// MODE 0: wave 128x48 (1M x 4N). MODE 1: wave 64x64 (2M x 2N).
template <int MODE>
__global__ __launch_bounds__(256, 2) void gemm_bt_kernel(
    const u16* __restrict__ A, const u16* __restrict__ B,
    u16* __restrict__ OQ, u16* __restrict__ OKb, u16* __restrict__ OVT,
    float* __restrict__ OF, int K, int N) {
  constexpr int BN = (MODE == 0) ? 192 : 128;
  constexpr int NA = (MODE == 0) ? 8 : 4;   // A fragments per wave
  constexpr int NB = (MODE == 0) ? 3 : 4;   // B fragments per wave
  constexpr int A_ISS = 4;                  // gload issues per wave for A (128 rows / (4w*8r))
  constexpr int B_ISS = BN / 32;            // 6 | 4
  constexpr int NBY = (MODE == 0) ? 8 : 4;

  __shared__ __align__(16) u16 As[2][128 * 64];
  __shared__ __align__(16) u16 Bs[2][BN * 64];

  const int tid = threadIdx.x;  // 0..255
  const int w = tid >> 6, lane = tid & 63;
  const int l15 = lane & 15, lg = lane >> 4;

  // XCD-chunked bijective swizzle, by fastest (A-panel L2 reuse per XCD)
  const int q8 = gridDim.x >> 3;
  const int wg = (blockIdx.x & 7) * q8 + (blockIdx.x >> 3);
  const int bx = wg / NBY, by = wg % NBY;

  // staging: per gload issue j (= i*4 + w): rows j*8..j*8+8; lane -> row j*8+(l>>3),
  // chunk l&7, source pre-swizzled by row&7 == l>>3 (constant per lane).
  const int srow = lane >> 3;
  const int schunk = (lane & 7) ^ srow;
  const u16* Ag = A + (size_t)(bx * 128 + srow) * K + schunk * 8;
  const u16* Bg = B + (size_t)(by * BN + srow) * K + schunk * 8;

  // hoisted swizzled LDS read offsets (loop-invariant)
  int aoff[NA][2], boff[NB][2];
#pragma unroll
  for (int mi = 0; mi < NA; ++mi)
#pragma unroll
    for (int ks = 0; ks < 2; ++ks) {
      const int row = ((MODE == 0) ? 0 : (w >> 1) * 64) + mi * 16 + l15;
      aoff[mi][ks] = row * 64 + (((ks * 4 + lg) ^ (row & 7)) * 8);
    }
#pragma unroll
  for (int ni = 0; ni < NB; ++ni)
#pragma unroll
    for (int ks = 0; ks < 2; ++ks) {
      const int row = ((MODE == 0) ? w * 48 : (w & 1) * 64) + ni * 16 + l15;
      boff[ni][ks] = row * 64 + (((ks * 4 + lg) ^ (row & 7)) * 8);
    }

  f32x4 acc[NA][NB] = {};

  const int nt = K >> 6;  // 8
#define STAGE(buf, k0)                                                        \
  {                                                                           \
    _Pragma("unroll") for (int i = 0; i < A_ISS; ++i) {                       \
      const int j = i * 4 + w;                                                \
      gload_lds16(Ag + (k0) + (size_t)(j * 8) * K, &As[buf][(j * 8) * 64]);   \
    }                                                                         \
    _Pragma("unroll") for (int i = 0; i < B_ISS; ++i) {                       \
      const int j = i * 4 + w;                                                \
      gload_lds16(Bg + (k0) + (size_t)(j * 8) * K, &Bs[buf][(j * 8) * 64]);   \
    }                                                                         \
  }
#define COMPUTE(cb)                                                           \
  {                                                                           \
    const u16* Ab = &As[cb][0];                                               \
    const u16* Bb = &Bs[cb][0];                                               \
    _Pragma("unroll") for (int ks = 0; ks < 2; ++ks) {                        \
      bf16x8 a[NA], b[NB];                                                    \
      _Pragma("unroll") for (int mi = 0; mi < NA; ++mi)                       \
          a[mi] = *(const bf16x8*)&Ab[aoff[mi][ks]];                          \
      _Pragma("unroll") for (int ni = 0; ni < NB; ++ni)                       \
          b[ni] = *(const bf16x8*)&Bb[boff[ni][ks]];                          \
      __builtin_amdgcn_s_setprio(1);                                          \
      _Pragma("unroll") for (int mi = 0; mi < NA; ++mi)                       \
          _Pragma("unroll") for (int ni = 0; ni < NB; ++ni)                   \
              acc[mi][ni] = __builtin_amdgcn_mfma_f32_16x16x32_bf16(           \
                  a[mi], b[ni], acc[mi][ni], 0, 0, 0);                        \
      __builtin_amdgcn_s_setprio(0);                                          \
    }                                                                         \
  }

  STAGE(0, 0);
  STAGE(1, 64);

  for (int t = 0; t < nt - 1; ++t) {
    // wait for STAGE(t); leave STAGE(t+1)'s (A_ISS+B_ISS) ops in flight
    if constexpr (A_ISS + B_ISS == 10)
      asm volatile("s_waitcnt vmcnt(10)" ::: "memory");
    else
      asm volatile("s_waitcnt vmcnt(8)" ::: "memory");
    __builtin_amdgcn_s_barrier();
    __builtin_amdgcn_sched_barrier(0);
    COMPUTE(t & 1);
    if (t + 2 < nt) {
      __builtin_amdgcn_s_barrier();  // all waves done reading buf t&1
      __builtin_amdgcn_sched_barrier(0);
      STAGE(t & 1, (t + 2) * 64);    // latency hides under COMPUTE(t+1)
    }
  }
  asm volatile("s_waitcnt vmcnt(0)" ::: "memory");
  __builtin_amdgcn_s_barrier();
  __builtin_amdgcn_sched_barrier(0);
  COMPUTE((nt - 1) & 1);
#undef STAGE
#undef COMPUTE

  if constexpr (MODE == 1) {
    const int row0 = bx * 128 + (w >> 1) * 64 + lg * 4;
#pragma unroll
    for (int mi = 0; mi < NA; ++mi)
#pragma unroll
      for (int ni = 0; ni < NB; ++ni) {
        int col = by * BN + (w & 1) * 64 + ni * 16 + l15;
#pragma unroll
        for (int r = 0; r < 4; ++r)
          OF[(size_t)(row0 + mi * 16 + r) * N + col] = acc[mi][ni][r];
      }
  } else {
    const int row0 = bx * 128 + lg * 4;
#pragma unroll
    for (int mi = 0; mi < NA; ++mi)
#pragma unroll
      for (int ni = 0; ni < NB; ++ni) {
        const int gcol = by * BN + w * 48 + ni * 16 + l15;
        const int sect = gcol >> 9;      // 0=q, 1=k, 2=v
        const int colL = gcol & 511;
        if (sect < 2) {
          u16* O = sect ? OKb : OQ;
#pragma unroll
          for (int r = 0; r < 4; ++r)
            O[(size_t)(row0 + mi * 16 + r) * 512 + colL] = f2bf(acc[mi][ni][r]);
        } else {
          int h = colL >> 6, dh = colL & 63;
          int rr = row0 + mi * 16;
          int bn = rr >> 10, t0 = rr & 1023;
          ushort4 pk;
          pk.x = f2bf(acc[mi][ni][0]);
          pk.y = f2bf(acc[mi][ni][1]);
          pk.z = f2bf(acc[mi][ni][2]);
          pk.w = f2bf(acc[mi][ni][3]);
          *(ushort4*)&OVT[(size_t)((bn * 8 + h) * 64 + dh) * 1024 + t0] = pk;
        }
      }
  }
}

// ---------------- fused flash attention v4 (round-9 verbatim): 32x32 MFMA, in-register P ----------------
// grid: 512 = 128 heads x 4 q-tiles of 256. block: 256 (4 waves x 64 q).
__global__ __launch_bounds__(256, 2) void attn_kernel(
    const u16* __restrict__ Qb, const u16* __restrict__ Kb, const u16* __restrict__ VTb,
    const u16* __restrict__ ekb, const u16* __restrict__ evb, u16* __restrict__ Ob) {
  __shared__ __align__(16) u16 Kl[64 * 64];
  __shared__ __align__(16) u16 Vl[64 * 64];

  const int tid = threadIdx.x;
  const int w = tid >> 6, lane = tid & 63;
  const int l31 = lane & 31, hi = lane >> 5;
  const int lb = (blockIdx.x & 7) * 64 + (blockIdx.x >> 3);
  const int head = lb >> 2, qt = lb & 3;
  const int bn = head >> 3, h = head & 7;
  const int q0 = qt * 256 + w * 64;

  const int sr = tid >> 3, sj = tid & 7;
  const int sdst = (sj ^ (sr & 7)) * 8;
  const u16* KgA = Kb + (size_t)(bn * 1024 + sr) * 512 + h * 64 + sj * 8;
  const u16* VgA = VTb + (size_t)(head * 64 + sr) * 1024 + sj * 8;
  u16* KlD = &Kl[sr * 64 + sdst];
  u16* VlD = &Vl[sr * 64 + sdst];

  uint4 kp0, kp1, vp0, vp1;
  {
    kp0 = *(const uint4*)(KgA);
    kp1 = *(const uint4*)(KgA + (size_t)32 * 512);
    vp0 = *(const uint4*)(VgA);
    vp1 = *(const uint4*)(VgA + (size_t)32 * 1024);
  }

  bf16x8 qf[2][4];
#pragma unroll
  for (int qs = 0; qs < 2; ++qs)
#pragma unroll
    for (int c = 0; c < 4; ++c)
      qf[qs][c] = *(const bf16x8*)(Qb + (size_t)(bn * 1024 + q0 + qs * 32 + l31) * 512 +
                                   h * 64 + c * 16 + hi * 8);

  bf16x8 bones1;
  {
    union { u16 u[8]; bf16x8 v; } ob;
#pragma unroll
    for (int j = 0; j < 8; ++j) ob.u[j] = (u16)0x3F80;
    bones1 = ob.v;
  }

  f32x16 acc[2][2];
  f32x16 acc5[2];
  {
    float dot[2] = {0.f, 0.f};
#pragma unroll
    for (int c = 0; c < 4; ++c) {
      bf16x8 ekf = *(const bf16x8*)(ekb + bn * 512 + h * 64 + c * 16 + hi * 8);
#pragma unroll
      for (int qs = 0; qs < 2; ++qs)
#pragma unroll
        for (int j = 0; j < 8; ++j)
          dot[qs] += (float)qf[qs][c][j] * (float)ekf[j];
    }
    union { u16 u[8]; bf16x8 v; } pef[2], evf[2];
#pragma unroll
    for (int qs = 0; qs < 2; ++qs) {
      uint32_t a = __builtin_bit_cast(uint32_t, dot[qs]), b = a;
      plswap(a, b);
      float part = (lane < 32) ? __builtin_bit_cast(float, b) : __builtin_bit_cast(float, a);
      float pe = exp2_fast(dot[qs] + part);
#pragma unroll
      for (int j = 0; j < 8; ++j) pef[qs].u[j] = 0;
      if (hi == 0) pef[qs].u[0] = f2bf(pe);
    }
#pragma unroll
    for (int dt = 0; dt < 2; ++dt) {
#pragma unroll
      for (int j = 0; j < 8; ++j) evf[dt].u[j] = 0;
      if (hi == 0) evf[dt].u[0] = evb[bn * 512 + h * 64 + dt * 32 + l31];
    }
    f32x16 z = {};
#pragma unroll
    for (int qs = 0; qs < 2; ++qs) {
#pragma unroll
      for (int dt = 0; dt < 2; ++dt)
        acc[qs][dt] = __builtin_amdgcn_mfma_f32_32x32x16_bf16(pef[qs].v, evf[dt].v, z, 0, 0, 0);
      acc5[qs] = __builtin_amdgcn_mfma_f32_32x32x16_bf16(pef[qs].v, bones1, z, 0, 0, 0);
    }
  }

  for (int jt = 0; jt < 16; ++jt) {
    __syncthreads();
    *(uint4*)(KlD) = kp0;
    *(uint4*)(KlD + 32 * 64) = kp1;
    *(uint4*)(VlD) = vp0;
    *(uint4*)(VlD + 32 * 64) = vp1;
    __syncthreads();

    if (jt < 15) {
      const int j0 = (jt + 1) * 64;
      kp0 = *(const uint4*)(KgA + (size_t)j0 * 512);
      kp1 = *(const uint4*)(KgA + (size_t)(j0 + 32) * 512);
      vp0 = *(const uint4*)(VgA + j0);
      vp1 = *(const uint4*)(VgA + j0 + (size_t)32 * 1024);
    }

#pragma unroll
    for (int sub = 0; sub < 2; ++sub) {
      const int rk = sub * 32 + l31;
      bf16x8 kb[4];
#pragma unroll
      for (int c = 0; c < 4; ++c)
        kb[c] = *(const bf16x8*)&Kl[rk * 64 + (((c * 2 + hi) ^ (rk & 7)) * 8)];

      f32x16 s[2] = {};
#pragma unroll
      for (int qs = 0; qs < 2; ++qs)
#pragma unroll
        for (int c = 0; c < 4; ++c)
          s[qs] = __builtin_amdgcn_mfma_f32_32x32x16_bf16(kb[c], qf[qs][c], s[qs], 0, 0, 0);

      bf16x8 pa[2][2];
#pragma unroll
      for (int qs = 0; qs < 2; ++qs) {
        uint32_t wd[8];
#pragma unroll
        for (int i = 0; i < 8; ++i)
          wd[i] = cvtpk(exp2_fast(s[qs][2 * i]), exp2_fast(s[qs][2 * i + 1]));
        plswap(wd[0], wd[2]);
        plswap(wd[1], wd[3]);
        plswap(wd[4], wd[6]);
        plswap(wd[5], wd[7]);
        union { uint32_t w[4]; bf16x8 v; } f0, f1;
        f0.w[0] = wd[0]; f0.w[1] = wd[1]; f0.w[2] = wd[2]; f0.w[3] = wd[3];
        f1.w[0] = wd[4]; f1.w[1] = wd[5]; f1.w[2] = wd[6]; f1.w[3] = wd[7];
        pa[qs][0] = f0.v;
        pa[qs][1] = f1.v;
      }

#pragma unroll
      for (int dt = 0; dt < 2; ++dt) {
        const int rv = dt * 32 + l31;
#pragma unroll
        for (int ch = 0; ch < 2; ++ch) {
          bf16x8 vb = *(const bf16x8*)&Vl[rv * 64 + (((sub * 4 + ch * 2 + hi) ^ (rv & 7)) * 8)];
#pragma unroll
          for (int qs = 0; qs < 2; ++qs)
            acc[qs][dt] = __builtin_amdgcn_mfma_f32_32x32x16_bf16(pa[qs][ch], vb, acc[qs][dt], 0, 0, 0);
        }
      }
#pragma unroll
      for (int qs = 0; qs < 2; ++qs)
#pragma unroll
        for (int ch = 0; ch < 2; ++ch)
          acc5[qs] = __builtin_amdgcn_mfma_f32_32x32x16_bf16(pa[qs][ch], bones1, acc5[qs], 0, 0, 0);
    }
  }

#pragma unroll
  for (int qs = 0; qs < 2; ++qs)
#pragma unroll
    for (int r = 0; r < 16; ++r) {
      const float inv = 1.0f / acc5[qs][r];
      const int q = q0 + qs * 32 + (r & 3) + 8 * (r >> 2) + 4 * hi;
      u16* op = Ob + (size_t)(bn * 1024 + q) * 512 + h * 64 + l31;
      op[0] = f2bf(acc[qs][0][r] * inv);
      op[32] = f2bf(acc[qs][1][r] * inv);
    }
}

// ---------------- launcher ----------------
extern "C" void kernel_launch(void* const* d_in, const int* in_sizes, int n_in,
                              void* d_out, int out_size, void* d_ws, size_t ws_size,
                              hipStream_t stream) {
  (void)in_sizes; (void)n_in; (void)out_size; (void)ws_size;
  const float* x     = (const float*)d_in[0];
  const float* label = (const float*)d_in[1];
  const float* Wqkv  = (const float*)d_in[2];
  const float* Wk    = (const float*)d_in[3];
  const float* Wv    = (const float*)d_in[4];
  const float* Wout  = (const float*)d_in[5];
  float* out = (float*)d_out;

  char* ws = (char*)d_ws;
  u16* xb    = (u16*)(ws);                 // 16 MB, reused as attention-out after GEMM1
  u16* WqkvT = (u16*)(ws + 16777216);      // 1.5 MB
  u16* WoutT = (u16*)(ws + 18350080);      // 0.5 MB
  u16* ekb   = (u16*)(ws + 18874368);      // 16 KB
  u16* evb   = (u16*)(ws + 18890752);      // 16 KB
  u16* Qbuf  = (u16*)(ws + 18907136);      // 16 MB
  u16* Kbuf  = (u16*)(ws + 35684352);      // 16 MB
  u16* VTbuf = (u16*)(ws + 52461568);      // 16 MB

  const float qscale = 0.125f * 1.4426950408889634f;

  prep_kernel<<<8448, 256, 0, stream>>>(x, Wqkv, Wout, label, Wk, Wv,
                                        xb, WqkvT, WoutT, ekb, evb, qscale);

  gemm_bt_kernel<0><<<1024, 256, 0, stream>>>(xb, WqkvT, Qbuf, Kbuf, VTbuf, nullptr, 512, 1536);

  attn_kernel<<<512, 256, 0, stream>>>(Qbuf, Kbuf, VTbuf, ekb, evb, xb);

  gemm_bt_kernel<1><<<512, 256, 0, stream>>>(xb, WoutT, nullptr, nullptr, nullptr, out, 512, 512);
}

// Round 16
// 117.112 us; speedup vs baseline: 1.0624x; 1.0008x over previous
//
#include <hip/hip_runtime.h>
#include <stdint.h>

typedef unsigned short u16;
typedef __bf16 bf16x8 __attribute__((ext_vector_type(8)));
typedef float f32x4 __attribute__((ext_vector_type(4)));
typedef float f32x16 __attribute__((ext_vector_type(16)));

__device__ __forceinline__ u16 f2bf(float f) {
  uint32_t u = __builtin_bit_cast(uint32_t, f);
  u += 0x7FFFu + ((u >> 16) & 1u);
  return (u16)(u >> 16);
}
__device__ __forceinline__ float bf2f(u16 v) {
  return __builtin_bit_cast(float, ((uint32_t)v) << 16);
}

#if __has_builtin(__builtin_amdgcn_exp2f)
__device__ __forceinline__ float exp2_fast(float x) { return __builtin_amdgcn_exp2f(x); }
#else
__device__ __forceinline__ float exp2_fast(float x) { return exp2f(x); }
#endif

__device__ __forceinline__ void gload_lds16(const u16* g, u16* l) {
  __builtin_amdgcn_global_load_lds(
      (const __attribute__((address_space(1))) uint32_t*)g,
      (__attribute__((address_space(3))) uint32_t*)l, 16, 0, 0);
}

__device__ __forceinline__ uint32_t cvtpk(float lo, float hi) {
  uint32_t r;
  asm("v_cvt_pk_bf16_f32 %0, %1, %2" : "=v"(r) : "v"(lo), "v"(hi));
  return r;
}
// v_permlane32_swap_b32: a.row1 <-> b.row0  (rows = 32-lane halves)
__device__ __forceinline__ void plswap(uint32_t& a, uint32_t& b) {
  asm volatile("v_permlane32_swap_b32 %0, %1" : "+v"(a), "+v"(b));
}

// ---------------- fused prep ----------------
// [0,4096): x->bf16 ; [4096,7168): WqkvT ; [7168,8192): WoutT ; [8192,8448): cond proj
__global__ __launch_bounds__(256) void prep_kernel(
    const float* __restrict__ x, const float* __restrict__ Wqkv,
    const float* __restrict__ Wout, const float* __restrict__ label,
    const float* __restrict__ Wk, const float* __restrict__ Wv,
    u16* __restrict__ xb, u16* __restrict__ WqkvT, u16* __restrict__ WoutT,
    u16* __restrict__ ek, u16* __restrict__ ev, float qscale) {
  const int b = blockIdx.x;
  if (b < 4096) {
    int i = (b * 256 + threadIdx.x) * 8;
    float4 a = *(const float4*)(x + i);
    float4 c = *(const float4*)(x + i + 4);
    union { u16 u[8]; uint4 v; } r;
    r.u[0] = f2bf(a.x); r.u[1] = f2bf(a.y); r.u[2] = f2bf(a.z); r.u[3] = f2bf(a.w);
    r.u[4] = f2bf(c.x); r.u[5] = f2bf(c.y); r.u[6] = f2bf(c.z); r.u[7] = f2bf(c.w);
    *(uint4*)(xb + i) = r.v;
  } else if (b < 7168) {
    int id = (b - 4096) * 256 + threadIdx.x;
    int k = id & 511, nn = id >> 9;
    float v = Wqkv[(size_t)k * 1536 + nn];
    if (nn < 512) v *= qscale;
    WqkvT[id] = f2bf(v);
  } else if (b < 8192) {
    int id = (b - 7168) * 256 + threadIdx.x;
    int k = id & 511, nn = id >> 9;
    WoutT[id] = f2bf(Wout[(size_t)k * 512 + nn]);
  } else {
    // cond proj: 256 blocks = 2 (k/v) x 16 rows x 8 col-chunks; 4-way K-split + LDS reduce
    __shared__ float sdata[256];
    const int bb = b - 8192;
    const int chunk = bb & 7, row = (bb >> 3) & 15;
    const float* W = (bb & 128) ? Wv : Wk;
    u16* o = (bb & 128) ? ev : ek;
    const int tid = threadIdx.x;
    const int col = chunk * 64 + (tid & 63);
    const int ks = tid >> 6;  // 0..3, 128 k each
    const float* lr = label + row * 512 + ks * 128;
    const float* wp = W + (size_t)(ks * 128) * 512 + col;
    float acc = 0.f;
#pragma unroll 8
    for (int i = 0; i < 128; ++i)
      acc = fmaf(lr[i], wp[(size_t)i * 512], acc);
    sdata[tid] = acc;
    __syncthreads();
    if (tid < 64) {
      float t = sdata[tid] + sdata[tid + 64] + sdata[tid + 128] + sdata[tid + 192];
      o[row * 512 + chunk * 64 + tid] = f2bf(t);
    }
  }
}

// ---------------- GEMM v5: BM=128 x BN(192|128), BK=64, 4 waves, 2 blocks/CU ----------------
// MODE 0: wave 128x48 (1M x 4N). MODE 1: wave 64x64 (2M x 2N).
template <int MODE>
__global__ __launch_bounds__(256, 2) void gemm_bt_kernel(
    const u16* __restrict__ A, const u16* __restrict__ B,
    u16* __restrict__ OQ, u16* __restrict__ OKb, u16* __restrict__ OVT,
    float* __restrict__ OF, int K, int N) {
  constexpr int BN = (MODE == 0) ? 192 : 128;
  constexpr int NA = (MODE == 0) ? 8 : 4;   // A fragments per wave
  constexpr int NB = (MODE == 0) ? 3 : 4;   // B fragments per wave
  constexpr int A_ISS = 4;
  constexpr int B_ISS = BN / 32;            // 6 | 4
  constexpr int NBY = (MODE == 0) ? 8 : 4;

  __shared__ __align__(16) u16 As[2][128 * 64];
  __shared__ __align__(16) u16 Bs[2][BN * 64];

  const int tid = threadIdx.x;  // 0..255
  const int w = tid >> 6, lane = tid & 63;
  const int l15 = lane & 15, lg = lane >> 4;

  const int q8 = gridDim.x >> 3;
  const int wg = (blockIdx.x & 7) * q8 + (blockIdx.x >> 3);
  const int bx = wg / NBY, by = wg % NBY;

  const int srow = lane >> 3;
  const int schunk = (lane & 7) ^ srow;
  const u16* Ag = A + (size_t)(bx * 128 + srow) * K + schunk * 8;
  const u16* Bg = B + (size_t)(by * BN + srow) * K + schunk * 8;

  int aoff[NA][2], boff[NB][2];
#pragma unroll
  for (int mi = 0; mi < NA; ++mi)
#pragma unroll
    for (int ks = 0; ks < 2; ++ks) {
      const int row = ((MODE == 0) ? 0 : (w >> 1) * 64) + mi * 16 + l15;
      aoff[mi][ks] = row * 64 + (((ks * 4 + lg) ^ (row & 7)) * 8);
    }
#pragma unroll
  for (int ni = 0; ni < NB; ++ni)
#pragma unroll
    for (int ks = 0; ks < 2; ++ks) {
      const int row = ((MODE == 0) ? w * 48 : (w & 1) * 64) + ni * 16 + l15;
      boff[ni][ks] = row * 64 + (((ks * 4 + lg) ^ (row & 7)) * 8);
    }

  f32x4 acc[NA][NB] = {};

  const int nt = K >> 6;  // 8
#define STAGE(buf, k0)                                                        \
  {                                                                           \
    _Pragma("unroll") for (int i = 0; i < A_ISS; ++i) {                       \
      const int j = i * 4 + w;                                                \
      gload_lds16(Ag + (k0) + (size_t)(j * 8) * K, &As[buf][(j * 8) * 64]);   \
    }                                                                         \
    _Pragma("unroll") for (int i = 0; i < B_ISS; ++i) {                       \
      const int j = i * 4 + w;                                                \
      gload_lds16(Bg + (k0) + (size_t)(j * 8) * K, &Bs[buf][(j * 8) * 64]);   \
    }                                                                         \
  }
#define COMPUTE(cb)                                                           \
  {                                                                           \
    const u16* Ab = &As[cb][0];                                               \
    const u16* Bb = &Bs[cb][0];                                               \
    _Pragma("unroll") for (int ks = 0; ks < 2; ++ks) {                        \
      bf16x8 a[NA], b[NB];                                                    \
      _Pragma("unroll") for (int mi = 0; mi < NA; ++mi)                       \
          a[mi] = *(const bf16x8*)&Ab[aoff[mi][ks]];                          \
      _Pragma("unroll") for (int ni = 0; ni < NB; ++ni)                       \
          b[ni] = *(const bf16x8*)&Bb[boff[ni][ks]];                          \
      __builtin_amdgcn_s_setprio(1);                                          \
      _Pragma("unroll") for (int mi = 0; mi < NA; ++mi)                       \
          _Pragma("unroll") for (int ni = 0; ni < NB; ++ni)                   \
              acc[mi][ni] = __builtin_amdgcn_mfma_f32_16x16x32_bf16(           \
                  a[mi], b[ni], acc[mi][ni], 0, 0, 0);                        \
      __builtin_amdgcn_s_setprio(0);                                          \
    }                                                                         \
  }

  STAGE(0, 0);
  STAGE(1, 64);

  for (int t = 0; t < nt - 1; ++t) {
    if constexpr (A_ISS + B_ISS == 10)
      asm volatile("s_waitcnt vmcnt(10)" ::: "memory");
    else
      asm volatile("s_waitcnt vmcnt(8)" ::: "memory");
    __builtin_amdgcn_s_barrier();
    __builtin_amdgcn_sched_barrier(0);
    COMPUTE(t & 1);
    if (t + 2 < nt) {
      __builtin_amdgcn_s_barrier();
      __builtin_amdgcn_sched_barrier(0);
      STAGE(t & 1, (t + 2) * 64);
    }
  }
  asm volatile("s_waitcnt vmcnt(0)" ::: "memory");
  __builtin_amdgcn_s_barrier();
  __builtin_amdgcn_sched_barrier(0);
  COMPUTE((nt - 1) & 1);
#undef STAGE
#undef COMPUTE

  if constexpr (MODE == 1) {
    const int row0 = bx * 128 + (w >> 1) * 64 + lg * 4;
#pragma unroll
    for (int mi = 0; mi < NA; ++mi)
#pragma unroll
      for (int ni = 0; ni < NB; ++ni) {
        int col = by * BN + (w & 1) * 64 + ni * 16 + l15;
#pragma unroll
        for (int r = 0; r < 4; ++r)
          OF[(size_t)(row0 + mi * 16 + r) * N + col] = acc[mi][ni][r];
      }
  } else {
    const int row0 = bx * 128 + lg * 4;
#pragma unroll
    for (int mi = 0; mi < NA; ++mi)
#pragma unroll
      for (int ni = 0; ni < NB; ++ni) {
        const int gcol = by * BN + w * 48 + ni * 16 + l15;
        const int sect = gcol >> 9;      // 0=q, 1=k, 2=v
        const int colL = gcol & 511;
        if (sect < 2) {
          u16* O = sect ? OKb : OQ;
#pragma unroll
          for (int r = 0; r < 4; ++r)
            O[(size_t)(row0 + mi * 16 + r) * 512 + colL] = f2bf(acc[mi][ni][r]);
        } else {
          int h = colL >> 6, dh = colL & 63;
          int rr = row0 + mi * 16;
          int bn = rr >> 10, t0 = rr & 1023;
          ushort4 pk;
          pk.x = f2bf(acc[mi][ni][0]);
          pk.y = f2bf(acc[mi][ni][1]);
          pk.z = f2bf(acc[mi][ni][2]);
          pk.w = f2bf(acc[mi][ni][3]);
          *(ushort4*)&OVT[(size_t)((bn * 8 + h) * 64 + dh) * 1024 + t0] = pk;
        }
      }
  }
}

// ---------------- fused flash attention v10: round-13 compute + v6/v7-verified dbuf gload_lds ----------------
// grid: 512 = 128 heads x 4 q-tiles of 256. block: 256 (4 waves x 64 q).
// Staging: 4-wave gload_lds (v6-verified geometry) into double buffer with ONE
// __syncthreads per tile (v7-verified handoff: barrier's vmcnt(0) drain covers DMA).
// Compute/rowsum(acc5)/prologue/epilogue: round-13 verbatim.
__global__ __launch_bounds__(256, 2) void attn_kernel(
    const u16* __restrict__ Qb, const u16* __restrict__ Kb, const u16* __restrict__ VTb,
    const u16* __restrict__ ekb, const u16* __restrict__ evb, u16* __restrict__ Ob) {
  __shared__ __align__(16) u16 Kl[2][64 * 64];
  __shared__ __align__(16) u16 Vl[2][64 * 64];

  const int tid = threadIdx.x;
  const int w = tid >> 6, lane = tid & 63;
  const int l31 = lane & 31, hi = lane >> 5;
  const int lb = (blockIdx.x & 7) * 64 + (blockIdx.x >> 3);
  const int head = lb >> 2, qt = lb & 3;
  const int bn = head >> 3, h = head & 7;
  const int q0 = qt * 256 + w * 64;

  // ---- gload_lds staging (v6-verified): wave w covers rows [w*16, w*16+16), 2 issues of 8 ----
  // (w*16 + i*8 + srow) & 7 == srow, so source swizzle column is lane-constant.
  const int srow = lane >> 3;
  const int scol = ((lane & 7) ^ srow) * 8;
  const u16* Kg0 = Kb + (size_t)(bn * 1024 + w * 16 + srow) * 512 + h * 64 + scol;
  const u16* Vg0 = VTb + (size_t)(head * 64 + w * 16 + srow) * 1024 + scol;

#define STAGE(buf, j0)                                                      \
  {                                                                         \
    gload_lds16(Kg0 + (size_t)(j0) * 512, &Kl[buf][(w * 16) * 64]);         \
    gload_lds16(Kg0 + (size_t)((j0) + 8) * 512, &Kl[buf][(w * 16 + 8) * 64]); \
    gload_lds16(Vg0 + (j0), &Vl[buf][(w * 16) * 64]);                       \
    gload_lds16(Vg0 + (j0) + (size_t)8 * 1024, &Vl[buf][(w * 16 + 8) * 64]); \
  }

  STAGE(0, 0);  // tile-0 DMA in flight under the prologue

  bf16x8 qf[2][4];
#pragma unroll
  for (int qs = 0; qs < 2; ++qs)
#pragma unroll
    for (int c = 0; c < 4; ++c)
      qf[qs][c] = *(const bf16x8*)(Qb + (size_t)(bn * 1024 + q0 + qs * 32 + l31) * 512 +
                                   h * 64 + c * 16 + hi * 8);

  bf16x8 bones1;
  {
    union { u16 u[8]; bf16x8 v; } ob;
#pragma unroll
    for (int j = 0; j < 8; ++j) ob.u[j] = (u16)0x3F80;
    bones1 = ob.v;
  }

  // ---- conditioning token prologue (round-13 verbatim) ----
  f32x16 acc[2][2];
  f32x16 acc5[2];
  {
    float dot[2] = {0.f, 0.f};
#pragma unroll
    for (int c = 0; c < 4; ++c) {
      bf16x8 ekf = *(const bf16x8*)(ekb + bn * 512 + h * 64 + c * 16 + hi * 8);
#pragma unroll
      for (int qs = 0; qs < 2; ++qs)
#pragma unroll
        for (int j = 0; j < 8; ++j)
          dot[qs] += (float)qf[qs][c][j] * (float)ekf[j];
    }
    union { u16 u[8]; bf16x8 v; } pef[2], evf[2];
#pragma unroll
    for (int qs = 0; qs < 2; ++qs) {
      uint32_t a = __builtin_bit_cast(uint32_t, dot[qs]), b = a;
      plswap(a, b);
      float part = (lane < 32) ? __builtin_bit_cast(float, b) : __builtin_bit_cast(float, a);
      float pe = exp2_fast(dot[qs] + part);
#pragma unroll
      for (int j = 0; j < 8; ++j) pef[qs].u[j] = 0;
      if (hi == 0) pef[qs].u[0] = f2bf(pe);
    }
#pragma unroll
    for (int dt = 0; dt < 2; ++dt) {
#pragma unroll
      for (int j = 0; j < 8; ++j) evf[dt].u[j] = 0;
      if (hi == 0) evf[dt].u[0] = evb[bn * 512 + h * 64 + dt * 32 + l31];
    }
    f32x16 z = {};
#pragma unroll
    for (int qs = 0; qs < 2; ++qs) {
#pragma unroll
      for (int dt = 0; dt < 2; ++dt)
        acc[qs][dt] = __builtin_amdgcn_mfma_f32_32x32x16_bf16(pef[qs].v, evf[dt].v, z, 0, 0, 0);
      acc5[qs] = __builtin_amdgcn_mfma_f32_32x32x16_bf16(pef[qs].v, bones1, z, 0, 0, 0);
    }
  }

  __syncthreads();  // tile-0 DMA drained (vmcnt 0) & visible

  // ---- main loop: 16 K/V tiles of 64; dbuf, ONE barrier per tile (v7-verified) ----
  for (int jt = 0; jt < 16; ++jt) {
    const int buf = jt & 1;
    if (jt < 15) STAGE(buf ^ 1, (jt + 1) * 64);  // DMA overlaps compute below

#pragma unroll
    for (int sub = 0; sub < 2; ++sub) {
      const int rk = sub * 32 + l31;
      bf16x8 kb[4];
#pragma unroll
      for (int c = 0; c < 4; ++c)
        kb[c] = *(const bf16x8*)&Kl[buf][rk * 64 + (((c * 2 + hi) ^ (rk & 7)) * 8)];

      f32x16 s[2] = {};
#pragma unroll
      for (int qs = 0; qs < 2; ++qs)
#pragma unroll
        for (int c = 0; c < 4; ++c)
          s[qs] = __builtin_amdgcn_mfma_f32_32x32x16_bf16(kb[c], qf[qs][c], s[qs], 0, 0, 0);

      bf16x8 pa[2][2];
#pragma unroll
      for (int qs = 0; qs < 2; ++qs) {
        uint32_t wd[8];
#pragma unroll
        for (int i = 0; i < 8; ++i)
          wd[i] = cvtpk(exp2_fast(s[qs][2 * i]), exp2_fast(s[qs][2 * i + 1]));
        plswap(wd[0], wd[2]);
        plswap(wd[1], wd[3]);
        plswap(wd[4], wd[6]);
        plswap(wd[5], wd[7]);
        union { uint32_t w[4]; bf16x8 v; } f0, f1;
        f0.w[0] = wd[0]; f0.w[1] = wd[1]; f0.w[2] = wd[2]; f0.w[3] = wd[3];
        f1.w[0] = wd[4]; f1.w[1] = wd[5]; f1.w[2] = wd[6]; f1.w[3] = wd[7];
        pa[qs][0] = f0.v;
        pa[qs][1] = f1.v;
      }

#pragma unroll
      for (int dt = 0; dt < 2; ++dt) {
        const int rv = dt * 32 + l31;
#pragma unroll
        for (int ch = 0; ch < 2; ++ch) {
          bf16x8 vb = *(const bf16x8*)&Vl[buf][rv * 64 + (((sub * 4 + ch * 2 + hi) ^ (rv & 7)) * 8)];
#pragma unroll
          for (int qs = 0; qs < 2; ++qs)
            acc[qs][dt] = __builtin_amdgcn_mfma_f32_32x32x16_bf16(pa[qs][ch], vb, acc[qs][dt], 0, 0, 0);
        }
      }
#pragma unroll
      for (int qs = 0; qs < 2; ++qs)
#pragma unroll
        for (int ch = 0; ch < 2; ++ch)
          acc5[qs] = __builtin_amdgcn_mfma_f32_32x32x16_bf16(pa[qs][ch], bones1, acc5[qs], 0, 0, 0);
    }

    __syncthreads();  // reads of buf done + DMA to buf^1 drained (vmcnt 0)
  }
#undef STAGE

  // ---- normalize + store (round-13 verbatim) ----
#pragma unroll
  for (int qs = 0; qs < 2; ++qs)
#pragma unroll
    for (int r = 0; r < 16; ++r) {
      const float inv = 1.0f / acc5[qs][r];
      const int q = q0 + qs * 32 + (r & 3) + 8 * (r >> 2) + 4 * hi;
      u16* op = Ob + (size_t)(bn * 1024 + q) * 512 + h * 64 + l31;
      op[0] = f2bf(acc[qs][0][r] * inv);
      op[32] = f2bf(acc[qs][1][r] * inv);
    }
}

// ---------------- launcher ----------------
extern "C" void kernel_launch(void* const* d_in, const int* in_sizes, int n_in,
                              void* d_out, int out_size, void* d_ws, size_t ws_size,
                              hipStream_t stream) {
  (void)in_sizes; (void)n_in; (void)out_size; (void)ws_size;
  const float* x     = (const float*)d_in[0];
  const float* label = (const float*)d_in[1];
  const float* Wqkv  = (const float*)d_in[2];
  const float* Wk    = (const float*)d_in[3];
  const float* Wv    = (const float*)d_in[4];
  const float* Wout  = (const float*)d_in[5];
  float* out = (float*)d_out;

  char* ws = (char*)d_ws;
  u16* xb    = (u16*)(ws);                 // 16 MB, reused as attention-out after GEMM1
  u16* WqkvT = (u16*)(ws + 16777216);      // 1.5 MB
  u16* WoutT = (u16*)(ws + 18350080);      // 0.5 MB
  u16* ekb   = (u16*)(ws + 18874368);      // 16 KB
  u16* evb   = (u16*)(ws + 18890752);      // 16 KB
  u16* Qbuf  = (u16*)(ws + 18907136);      // 16 MB
  u16* Kbuf  = (u16*)(ws + 35684352);      // 16 MB
  u16* VTbuf = (u16*)(ws + 52461568);      // 16 MB

  const float qscale = 0.125f * 1.4426950408889634f;

  prep_kernel<<<8448, 256, 0, stream>>>(x, Wqkv, Wout, label, Wk, Wv,
                                        xb, WqkvT, WoutT, ekb, evb, qscale);

  gemm_bt_kernel<0><<<1024, 256, 0, stream>>>(xb, WqkvT, Qbuf, Kbuf, VTbuf, nullptr, 512, 1536);

  attn_kernel<<<512, 256, 0, stream>>>(Qbuf, Kbuf, VTbuf, ekb, evb, xb);

  gemm_bt_kernel<1><<<512, 256, 0, stream>>>(xb, WoutT, nullptr, nullptr, nullptr, out, 512, 512);
}

// Round 17
// 116.836 us; speedup vs baseline: 1.0649x; 1.0024x over previous
//
#include <hip/hip_runtime.h>
#include <stdint.h>

typedef unsigned short u16;
typedef __bf16 bf16x8 __attribute__((ext_vector_type(8)));
typedef float f32x4 __attribute__((ext_vector_type(4)));
typedef float f32x16 __attribute__((ext_vector_type(16)));

__device__ __forceinline__ u16 f2bf(float f) {
  uint32_t u = __builtin_bit_cast(uint32_t, f);
  u += 0x7FFFu + ((u >> 16) & 1u);
  return (u16)(u >> 16);
}
__device__ __forceinline__ float bf2f(u16 v) {
  return __builtin_bit_cast(float, ((uint32_t)v) << 16);
}

#if __has_builtin(__builtin_amdgcn_exp2f)
__device__ __forceinline__ float exp2_fast(float x) { return __builtin_amdgcn_exp2f(x); }
#else
__device__ __forceinline__ float exp2_fast(float x) { return exp2f(x); }
#endif

__device__ __forceinline__ void gload_lds16(const u16* g, u16* l) {
  __builtin_amdgcn_global_load_lds(
      (const __attribute__((address_space(1))) uint32_t*)g,
      (__attribute__((address_space(3))) uint32_t*)l, 16, 0, 0);
}

__device__ __forceinline__ uint32_t cvtpk(float lo, float hi) {
  uint32_t r;
  asm("v_cvt_pk_bf16_f32 %0, %1, %2" : "=v"(r) : "v"(lo), "v"(hi));
  return r;
}
// v_permlane32_swap_b32: a.row1 <-> b.row0  (rows = 32-lane halves)
__device__ __forceinline__ void plswap(uint32_t& a, uint32_t& b) {
  asm volatile("v_permlane32_swap_b32 %0, %1" : "+v"(a), "+v"(b));
}

// ---------------- fused prep ----------------
// [0,4096): x->bf16 ; [4096,7168): WqkvT ; [7168,8192): WoutT ; [8192,8448): cond proj
__global__ __launch_bounds__(256) void prep_kernel(
    const float* __restrict__ x, const float* __restrict__ Wqkv,
    const float* __restrict__ Wout, const float* __restrict__ label,
    const float* __restrict__ Wk, const float* __restrict__ Wv,
    u16* __restrict__ xb, u16* __restrict__ WqkvT, u16* __restrict__ WoutT,
    u16* __restrict__ ek, u16* __restrict__ ev, float qscale) {
  const int b = blockIdx.x;
  if (b < 4096) {
    int i = (b * 256 + threadIdx.x) * 8;
    float4 a = *(const float4*)(x + i);
    float4 c = *(const float4*)(x + i + 4);
    union { u16 u[8]; uint4 v; } r;
    r.u[0] = f2bf(a.x); r.u[1] = f2bf(a.y); r.u[2] = f2bf(a.z); r.u[3] = f2bf(a.w);
    r.u[4] = f2bf(c.x); r.u[5] = f2bf(c.y); r.u[6] = f2bf(c.z); r.u[7] = f2bf(c.w);
    *(uint4*)(xb + i) = r.v;
  } else if (b < 7168) {
    int id = (b - 4096) * 256 + threadIdx.x;
    int k = id & 511, nn = id >> 9;
    float v = Wqkv[(size_t)k * 1536 + nn];
    if (nn < 512) v *= qscale;
    WqkvT[id] = f2bf(v);
  } else if (b < 8192) {
    int id = (b - 7168) * 256 + threadIdx.x;
    int k = id & 511, nn = id >> 9;
    WoutT[id] = f2bf(Wout[(size_t)k * 512 + nn]);
  } else {
    // cond proj: 256 blocks = 2 (k/v) x 16 rows x 8 col-chunks; 4-way K-split + LDS reduce
    __shared__ float sdata[256];
    const int bb = b - 8192;
    const int chunk = bb & 7, row = (bb >> 3) & 15;
    const float* W = (bb & 128) ? Wv : Wk;
    u16* o = (bb & 128) ? ev : ek;
    const int tid = threadIdx.x;
    const int col = chunk * 64 + (tid & 63);
    const int ks = tid >> 6;  // 0..3, 128 k each
    const float* lr = label + row * 512 + ks * 128;
    const float* wp = W + (size_t)(ks * 128) * 512 + col;
    float acc = 0.f;
#pragma unroll 8
    for (int i = 0; i < 128; ++i)
      acc = fmaf(lr[i], wp[(size_t)i * 512], acc);
    sdata[tid] = acc;
    __syncthreads();
    if (tid < 64) {
      float t = sdata[tid] + sdata[tid + 64] + sdata[tid + 128] + sdata[tid + 192];
      o[row * 512 + chunk * 64 + tid] = f2bf(t);
    }
  }
}

// ---------------- GEMM v5: BM=128 x BN(192|128), BK=64, 4 waves, 2 blocks/CU ----------------
// MODE 0: wave 128x48 (1M x 4N). MODE 1: wave 64x64 (2M x 2N).
template <int MODE>
__global__ __launch_bounds__(256, 2) void gemm_bt_kernel(
    const u16* __restrict__ A, const u16* __restrict__ B,
    u16* __restrict__ OQ, u16* __restrict__ OKb, u16* __restrict__ OVT,
    float* __restrict__ OF, int K, int N) {
  constexpr int BN = (MODE == 0) ? 192 : 128;
  constexpr int NA = (MODE == 0) ? 8 : 4;   // A fragments per wave
  constexpr int NB = (MODE == 0) ? 3 : 4;   // B fragments per wave
  constexpr int A_ISS = 4;
  constexpr int B_ISS = BN / 32;            // 6 | 4
  constexpr int NBY = (MODE == 0) ? 8 : 4;

  __shared__ __align__(16) u16 As[2][128 * 64];
  __shared__ __align__(16) u16 Bs[2][BN * 64];

  const int tid = threadIdx.x;  // 0..255
  const int w = tid >> 6, lane = tid & 63;
  const int l15 = lane & 15, lg = lane >> 4;

  const int q8 = gridDim.x >> 3;
  const int wg = (blockIdx.x & 7) * q8 + (blockIdx.x >> 3);
  const int bx = wg / NBY, by = wg % NBY;

  const int srow = lane >> 3;
  const int schunk = (lane & 7) ^ srow;
  const u16* Ag = A + (size_t)(bx * 128 + srow) * K + schunk * 8;
  const u16* Bg = B + (size_t)(by * BN + srow) * K + schunk * 8;

  int aoff[NA][2], boff[NB][2];
#pragma unroll
  for (int mi = 0; mi < NA; ++mi)
#pragma unroll
    for (int ks = 0; ks < 2; ++ks) {
      const int row = ((MODE == 0) ? 0 : (w >> 1) * 64) + mi * 16 + l15;
      aoff[mi][ks] = row * 64 + (((ks * 4 + lg) ^ (row & 7)) * 8);
    }
#pragma unroll
  for (int ni = 0; ni < NB; ++ni)
#pragma unroll
    for (int ks = 0; ks < 2; ++ks) {
      const int row = ((MODE == 0) ? w * 48 : (w & 1) * 64) + ni * 16 + l15;
      boff[ni][ks] = row * 64 + (((ks * 4 + lg) ^ (row & 7)) * 8);
    }

  f32x4 acc[NA][NB] = {};

  const int nt = K >> 6;  // 8
#define STAGE(buf, k0)                                                        \
  {                                                                           \
    _Pragma("unroll") for (int i = 0; i < A_ISS; ++i) {                       \
      const int j = i * 4 + w;                                                \
      gload_lds16(Ag + (k0) + (size_t)(j * 8) * K, &As[buf][(j * 8) * 64]);   \
    }                                                                         \
    _Pragma("unroll") for (int i = 0; i < B_ISS; ++i) {                       \
      const int j = i * 4 + w;                                                \
      gload_lds16(Bg + (k0) + (size_t)(j * 8) * K, &Bs[buf][(j * 8) * 64]);   \
    }                                                                         \
  }
#define COMPUTE(cb)                                                           \
  {                                                                           \
    const u16* Ab = &As[cb][0];                                               \
    const u16* Bb = &Bs[cb][0];                                               \
    _Pragma("unroll") for (int ks = 0; ks < 2; ++ks) {                        \
      bf16x8 a[NA], b[NB];                                                    \
      _Pragma("unroll") for (int mi = 0; mi < NA; ++mi)                       \
          a[mi] = *(const bf16x8*)&Ab[aoff[mi][ks]];                          \
      _Pragma("unroll") for (int ni = 0; ni < NB; ++ni)                       \
          b[ni] = *(const bf16x8*)&Bb[boff[ni][ks]];                          \
      __builtin_amdgcn_s_setprio(1);                                          \
      _Pragma("unroll") for (int mi = 0; mi < NA; ++mi)                       \
          _Pragma("unroll") for (int ni = 0; ni < NB; ++ni)                   \
              acc[mi][ni] = __builtin_amdgcn_mfma_f32_16x16x32_bf16(           \
                  a[mi], b[ni], acc[mi][ni], 0, 0, 0);                        \
      __builtin_amdgcn_s_setprio(0);                                          \
    }                                                                         \
  }

  STAGE(0, 0);
  STAGE(1, 64);

  for (int t = 0; t < nt - 1; ++t) {
    if constexpr (A_ISS + B_ISS == 10)
      asm volatile("s_waitcnt vmcnt(10)" ::: "memory");
    else
      asm volatile("s_waitcnt vmcnt(8)" ::: "memory");
    __builtin_amdgcn_s_barrier();
    __builtin_amdgcn_sched_barrier(0);
    COMPUTE(t & 1);
    if (t + 2 < nt) {
      __builtin_amdgcn_s_barrier();
      __builtin_amdgcn_sched_barrier(0);
      STAGE(t & 1, (t + 2) * 64);
    }
  }
  asm volatile("s_waitcnt vmcnt(0)" ::: "memory");
  __builtin_amdgcn_s_barrier();
  __builtin_amdgcn_sched_barrier(0);
  COMPUTE((nt - 1) & 1);
#undef STAGE
#undef COMPUTE

  if constexpr (MODE == 1) {
    const int row0 = bx * 128 + (w >> 1) * 64 + lg * 4;
#pragma unroll
    for (int mi = 0; mi < NA; ++mi)
#pragma unroll
      for (int ni = 0; ni < NB; ++ni) {
        int col = by * BN + (w & 1) * 64 + ni * 16 + l15;
#pragma unroll
        for (int r = 0; r < 4; ++r)
          OF[(size_t)(row0 + mi * 16 + r) * N + col] = acc[mi][ni][r];
      }
  } else {
    const int row0 = bx * 128 + lg * 4;
#pragma unroll
    for (int mi = 0; mi < NA; ++mi)
#pragma unroll
      for (int ni = 0; ni < NB; ++ni) {
        const int gcol = by * BN + w * 48 + ni * 16 + l15;
        const int sect = gcol >> 9;      // 0=q, 1=k, 2=v
        const int colL = gcol & 511;
        if (sect < 2) {
          u16* O = sect ? OKb : OQ;
#pragma unroll
          for (int r = 0; r < 4; ++r)
            O[(size_t)(row0 + mi * 16 + r) * 512 + colL] = f2bf(acc[mi][ni][r]);
        } else {
          int h = colL >> 6, dh = colL & 63;
          int rr = row0 + mi * 16;
          int bn = rr >> 10, t0 = rr & 1023;
          ushort4 pk;
          pk.x = f2bf(acc[mi][ni][0]);
          pk.y = f2bf(acc[mi][ni][1]);
          pk.z = f2bf(acc[mi][ni][2]);
          pk.w = f2bf(acc[mi][ni][3]);
          *(ushort4*)&OVT[(size_t)((bn * 8 + h) * 64 + dh) * 1024 + t0] = pk;
        }
      }
  }
}

// ---------------- fused flash attention v11: round-13 verbatim + phase fission ----------------
// grid: 512 = 128 heads x 4 q-tiles of 256. block: 256 (4 waves x 64 q).
// Same staging/sync/math as round-13 (passing, 45.2us). Only change: the tile body is
// fissioned into 3 phases over both subs (QK all -> pack all -> PV+rowsum all) so waves
// in different phases co-issue MFMA vs VALU/trans work.
__global__ __launch_bounds__(256, 2) void attn_kernel(
    const u16* __restrict__ Qb, const u16* __restrict__ Kb, const u16* __restrict__ VTb,
    const u16* __restrict__ ekb, const u16* __restrict__ evb, u16* __restrict__ Ob) {
  __shared__ __align__(16) u16 Kl[64 * 64];
  __shared__ __align__(16) u16 Vl[64 * 64];

  const int tid = threadIdx.x;
  const int w = tid >> 6, lane = tid & 63;
  const int l31 = lane & 31, hi = lane >> 5;
  const int lb = (blockIdx.x & 7) * 64 + (blockIdx.x >> 3);
  const int head = lb >> 2, qt = lb & 3;
  const int bn = head >> 3, h = head & 7;
  const int q0 = qt * 256 + w * 64;

  const int sr = tid >> 3, sj = tid & 7;
  const int sdst = (sj ^ (sr & 7)) * 8;
  const u16* KgA = Kb + (size_t)(bn * 1024 + sr) * 512 + h * 64 + sj * 8;
  const u16* VgA = VTb + (size_t)(head * 64 + sr) * 1024 + sj * 8;
  u16* KlD = &Kl[sr * 64 + sdst];
  u16* VlD = &Vl[sr * 64 + sdst];

  uint4 kp0, kp1, vp0, vp1;
  {
    kp0 = *(const uint4*)(KgA);
    kp1 = *(const uint4*)(KgA + (size_t)32 * 512);
    vp0 = *(const uint4*)(VgA);
    vp1 = *(const uint4*)(VgA + (size_t)32 * 1024);
  }

  bf16x8 qf[2][4];
#pragma unroll
  for (int qs = 0; qs < 2; ++qs)
#pragma unroll
    for (int c = 0; c < 4; ++c)
      qf[qs][c] = *(const bf16x8*)(Qb + (size_t)(bn * 1024 + q0 + qs * 32 + l31) * 512 +
                                   h * 64 + c * 16 + hi * 8);

  bf16x8 bones1;
  {
    union { u16 u[8]; bf16x8 v; } ob;
#pragma unroll
    for (int j = 0; j < 8; ++j) ob.u[j] = (u16)0x3F80;
    bones1 = ob.v;
  }

  f32x16 acc[2][2];
  f32x16 acc5[2];
  {
    float dot[2] = {0.f, 0.f};
#pragma unroll
    for (int c = 0; c < 4; ++c) {
      bf16x8 ekf = *(const bf16x8*)(ekb + bn * 512 + h * 64 + c * 16 + hi * 8);
#pragma unroll
      for (int qs = 0; qs < 2; ++qs)
#pragma unroll
        for (int j = 0; j < 8; ++j)
          dot[qs] += (float)qf[qs][c][j] * (float)ekf[j];
    }
    union { u16 u[8]; bf16x8 v; } pef[2], evf[2];
#pragma unroll
    for (int qs = 0; qs < 2; ++qs) {
      uint32_t a = __builtin_bit_cast(uint32_t, dot[qs]), b = a;
      plswap(a, b);
      float part = (lane < 32) ? __builtin_bit_cast(float, b) : __builtin_bit_cast(float, a);
      float pe = exp2_fast(dot[qs] + part);
#pragma unroll
      for (int j = 0; j < 8; ++j) pef[qs].u[j] = 0;
      if (hi == 0) pef[qs].u[0] = f2bf(pe);
    }
#pragma unroll
    for (int dt = 0; dt < 2; ++dt) {
#pragma unroll
      for (int j = 0; j < 8; ++j) evf[dt].u[j] = 0;
      if (hi == 0) evf[dt].u[0] = evb[bn * 512 + h * 64 + dt * 32 + l31];
    }
    f32x16 z = {};
#pragma unroll
    for (int qs = 0; qs < 2; ++qs) {
#pragma unroll
      for (int dt = 0; dt < 2; ++dt)
        acc[qs][dt] = __builtin_amdgcn_mfma_f32_32x32x16_bf16(pef[qs].v, evf[dt].v, z, 0, 0, 0);
      acc5[qs] = __builtin_amdgcn_mfma_f32_32x32x16_bf16(pef[qs].v, bones1, z, 0, 0, 0);
    }
  }

  for (int jt = 0; jt < 16; ++jt) {
    __syncthreads();
    *(uint4*)(KlD) = kp0;
    *(uint4*)(KlD + 32 * 64) = kp1;
    *(uint4*)(VlD) = vp0;
    *(uint4*)(VlD + 32 * 64) = vp1;
    __syncthreads();

    if (jt < 15) {
      const int j0 = (jt + 1) * 64;
      kp0 = *(const uint4*)(KgA + (size_t)j0 * 512);
      kp1 = *(const uint4*)(KgA + (size_t)(j0 + 32) * 512);
      vp0 = *(const uint4*)(VgA + j0);
      vp1 = *(const uint4*)(VgA + j0 + (size_t)32 * 1024);
    }

    // ---- phase 1: QK^T for BOTH subs (4 independent MFMA chains) ----
    f32x16 s[2][2] = {};  // [sub][qs]
#pragma unroll
    for (int sub = 0; sub < 2; ++sub) {
      const int rk = sub * 32 + l31;
#pragma unroll
      for (int c = 0; c < 4; ++c) {
        bf16x8 kb = *(const bf16x8*)&Kl[rk * 64 + (((c * 2 + hi) ^ (rk & 7)) * 8)];
        s[sub][0] = __builtin_amdgcn_mfma_f32_32x32x16_bf16(kb, qf[0][c], s[sub][0], 0, 0, 0);
        s[sub][1] = __builtin_amdgcn_mfma_f32_32x32x16_bf16(kb, qf[1][c], s[sub][1], 0, 0, 0);
      }
    }

    // ---- phase 2: exp2 + pack + permlane for BOTH subs ----
    bf16x8 pa[2][2][2];  // [sub][qs][ch]
#pragma unroll
    for (int sub = 0; sub < 2; ++sub)
#pragma unroll
      for (int qs = 0; qs < 2; ++qs) {
        uint32_t wd[8];
#pragma unroll
        for (int i = 0; i < 8; ++i)
          wd[i] = cvtpk(exp2_fast(s[sub][qs][2 * i]), exp2_fast(s[sub][qs][2 * i + 1]));
        plswap(wd[0], wd[2]);
        plswap(wd[1], wd[3]);
        plswap(wd[4], wd[6]);
        plswap(wd[5], wd[7]);
        union { uint32_t w[4]; bf16x8 v; } f0, f1;
        f0.w[0] = wd[0]; f0.w[1] = wd[1]; f0.w[2] = wd[2]; f0.w[3] = wd[3];
        f1.w[0] = wd[4]; f1.w[1] = wd[5]; f1.w[2] = wd[6]; f1.w[3] = wd[7];
        pa[sub][qs][0] = f0.v;
        pa[sub][qs][1] = f1.v;
      }

    // ---- phase 3: PV + rowsum for BOTH subs ----
#pragma unroll
    for (int sub = 0; sub < 2; ++sub) {
#pragma unroll
      for (int dt = 0; dt < 2; ++dt) {
        const int rv = dt * 32 + l31;
#pragma unroll
        for (int ch = 0; ch < 2; ++ch) {
          bf16x8 vb = *(const bf16x8*)&Vl[rv * 64 + (((sub * 4 + ch * 2 + hi) ^ (rv & 7)) * 8)];
#pragma unroll
          for (int qs = 0; qs < 2; ++qs)
            acc[qs][dt] = __builtin_amdgcn_mfma_f32_32x32x16_bf16(pa[sub][qs][ch], vb, acc[qs][dt], 0, 0, 0);
        }
      }
#pragma unroll
      for (int qs = 0; qs < 2; ++qs)
#pragma unroll
        for (int ch = 0; ch < 2; ++ch)
          acc5[qs] = __builtin_amdgcn_mfma_f32_32x32x16_bf16(pa[sub][qs][ch], bones1, acc5[qs], 0, 0, 0);
    }
  }

#pragma unroll
  for (int qs = 0; qs < 2; ++qs)
#pragma unroll
    for (int r = 0; r < 16; ++r) {
      const float inv = 1.0f / acc5[qs][r];
      const int q = q0 + qs * 32 + (r & 3) + 8 * (r >> 2) + 4 * hi;
      u16* op = Ob + (size_t)(bn * 1024 + q) * 512 + h * 64 + l31;
      op[0] = f2bf(acc[qs][0][r] * inv);
      op[32] = f2bf(acc[qs][1][r] * inv);
    }
}

// ---------------- launcher ----------------
extern "C" void kernel_launch(void* const* d_in, const int* in_sizes, int n_in,
                              void* d_out, int out_size, void* d_ws, size_t ws_size,
                              hipStream_t stream) {
  (void)in_sizes; (void)n_in; (void)out_size; (void)ws_size;
  const float* x     = (const float*)d_in[0];
  const float* label = (const float*)d_in[1];
  const float* Wqkv  = (const float*)d_in[2];
  const float* Wk    = (const float*)d_in[3];
  const float* Wv    = (const float*)d_in[4];
  const float* Wout  = (const float*)d_in[5];
  float* out = (float*)d_out;

  char* ws = (char*)d_ws;
  u16* xb    = (u16*)(ws);                 // 16 MB, reused as attention-out after GEMM1
  u16* WqkvT = (u16*)(ws + 16777216);      // 1.5 MB
  u16* WoutT = (u16*)(ws + 18350080);      // 0.5 MB
  u16* ekb   = (u16*)(ws + 18874368);      // 16 KB
  u16* evb   = (u16*)(ws + 18890752);      // 16 KB
  u16* Qbuf  = (u16*)(ws + 18907136);      // 16 MB
  u16* Kbuf  = (u16*)(ws + 35684352);      // 16 MB
  u16* VTbuf = (u16*)(ws + 52461568);      // 16 MB

  const float qscale = 0.125f * 1.4426950408889634f;

  prep_kernel<<<8448, 256, 0, stream>>>(x, Wqkv, Wout, label, Wk, Wv,
                                        xb, WqkvT, WoutT, ekb, evb, qscale);

  gemm_bt_kernel<0><<<1024, 256, 0, stream>>>(xb, WqkvT, Qbuf, Kbuf, VTbuf, nullptr, 512, 1536);

  attn_kernel<<<512, 256, 0, stream>>>(Qbuf, Kbuf, VTbuf, ekb, evb, xb);

  gemm_bt_kernel<1><<<512, 256, 0, stream>>>(xb, WoutT, nullptr, nullptr, nullptr, out, 512, 512);
}